// Round 11
// baseline (1295.543 us; speedup 1.0000x reference)
//
#include <hip/hip_runtime.h>
#include <hip/hip_bf16.h>

#define VOCAB 29
#define VEC   512
#define HID   1024
#define SEN   64
#define BATCH 2048

typedef __bf16 bf16_t;
typedef bf16_t bf16x8 __attribute__((ext_vector_type(8)));
typedef float  floatx4 __attribute__((ext_vector_type(4)));

// ---------------- prep: W_hh fp32 -> bf16 ----------------
__global__ void cvt_whh(const float* __restrict__ w, bf16_t* __restrict__ o, int n) {
    int i = blockIdx.x * blockDim.x + threadIdx.x;
    if (i < n) o[i] = (bf16_t)w[i];
}

// ---------------- prep: W_cls fp32 [65][1024] -> bf16 padded [80][1024] ----------------
__global__ void cvt_wcls(const float* __restrict__ w, bf16_t* __restrict__ o) {
    int i = blockIdx.x * blockDim.x + threadIdx.x;
    if (i >= 80 * HID) return;
    o[i] = (i < 65 * HID) ? (bf16_t)w[i] : (bf16_t)0.0f;
}

// ---------------- prep: proj[v][h] = dot(emb[v], W_ih[h]) (fp32) ----------------
__global__ void proj_kernel(const float* __restrict__ emb, const float* __restrict__ wih,
                            float* __restrict__ proj) {
    int idx = blockIdx.x * blockDim.x + threadIdx.x;
    if (idx >= VOCAB * HID) return;
    int v = idx / HID, h = idx % HID;
    const float* e = emb + v * VEC;
    const float* w = wih + h * VEC;
    float s = 0.f;
    for (int k = 0; k < VEC; k += 4) {
        float4 ev = *(const float4*)(e + k);
        float4 wv = *(const float4*)(w + k);
        s += ev.x * wv.x + ev.y * wv.y + ev.z * wv.z + ev.w * wv.w;
    }
    proj[idx] = s;
}

// exact identity tanh(x) = 1 - 2/(exp(2x)+1); fp32 rounding error << bf16 ulp
__device__ __forceinline__ float fast_tanh(float x) {
    float e = __expf(2.0f * x);
    return 1.0f - 2.0f / (e + 1.0f);
}

// async global->LDS 16B copy. LDS dest: wave-uniform base + lane*16 (HW rule).
__device__ __forceinline__ void load16_to_lds(const bf16_t* g, bf16_t* l) {
    auto gp = reinterpret_cast<const __attribute__((address_space(1))) unsigned int*>(
        reinterpret_cast<uintptr_t>(g));
    auto lp = reinterpret_cast<__attribute__((address_space(3))) unsigned int*>(
        static_cast<unsigned int>(reinterpret_cast<uintptr_t>(l)));
    __builtin_amdgcn_global_load_lds(gp, lp, 16, 0, 0);
}

// ============================================================================
// v12: v11's balanced tiling in the 256-THREAD regime where the compiler
// keeps deep rings live (v5: 256thr->188 VGPR; all 512thr kernels: <=128,
// ring sunk -> v11's exposed-latency regression despite halved conflicts).
//   BN=32: Bsh[32][1024]=64KB -> 2 blocks/CU (grid (16,32)=512 blocks =
//   exactly 2x256 CU slots; LDS 2x64.5<=160KB; VGPR<=256 -> 2 waves/SIMD).
//   4 waves x (32m x 32n): per chunk 2 B ds_reads + 2 A loads + 4 MFMA.
//   Per CU/step: DS 512 reads (~2.9us+conf), A 512KB vmem (~3.7us, other
//   pipe), MFMA 2.07us -> balanced & overlappable. Depth-8 A ring (64 VGPR,
//   ~480cyc lookahead >= post-inv L2 latency). TLP: co-resident INDEPENDENT
//   block fills sync-spin/drain stalls.
//   Same-XCD panels hold: panel bx ids ≡ bx (mod 8) since gridDim.x=16.
//   Proven kept: swizzled DMA staging, panel counter sync (fast/safe),
//   per-step buffer_inv, ascending chunk order (numerics identical).
// ============================================================================
#define BM 128
#define BN 32
#define PANEL_BLKS 32
#define SB() __builtin_amdgcn_sched_barrier(0)

__global__ __launch_bounds__(256)
void rnn_persist(const bf16_t* __restrict__ whh, const float* __restrict__ proj,
                 const int* __restrict__ x, bf16_t* hbuf, int* scnt)
{
    __shared__ __align__(16) bf16_t Bsh[BN][HID];   // 64 KB -> 2 blocks/CU
    __shared__ int uni_sh;

    const int tid  = threadIdx.x;
    const int bx   = blockIdx.x, by = blockIdx.y;
    const int m0   = bx * BM;
    const int n0   = by * BN;
    const int wave = tid >> 6;         // 4 waves
    const int lane = tid & 63;
    const int q    = lane >> 4;
    const int l16  = lane & 15;
    const int l7   = l16 & 7;
    const int mpos = wave;             // 4 m-positions x 32 rows

    int* cnt   = scnt + bx * 64;            // per-panel counter (256B stride)
    int* xmask = scnt + (16 + bx) * 64;     // per-panel XCD mask

    // ---- stage W_hh slice ONCE: wave handles row r = it*4+wave, 2 halves.
    //      Dest lane-linear (DMA rule), source 16B-chunk XOR'd: phys = glob ^ (r&7).
#pragma unroll
    for (int half = 0; half < 2; half++)
#pragma unroll
        for (int it = 0; it < 8; it++) {
            const int r = it * 4 + wave;
            load16_to_lds(whh + (n0 + r) * HID + half * 512 + (lane ^ (r & 7)) * 8,
                          &Bsh[r][half * 512 + lane * 8]);
        }

    // rows this lane owns (C/D row = q*4+reg within each 16-row m-frag)
    int rowl[8];
#pragma unroll
    for (int mf = 0; mf < 2; mf++)
#pragma unroll
        for (int r = 0; r < 4; r++)
            rowl[mf * 4 + r] = m0 + mpos * 32 + mf * 16 + q * 4 + r;
    const int ncol0 = n0 + l16;   // + ni*16, ni = 0,1

    // ---- t = 0: h = tanh(proj[x[:,0]]) (h_prev = 0); 8 rows x 2 cols/lane
#pragma unroll
    for (int i = 0; i < 8; i++) {
        const int tok = x[rowl[i] * SEN + 0];
#pragma unroll
        for (int ni = 0; ni < 2; ni++) {
            const float v = proj[tok * HID + ncol0 + ni * 16];
            hbuf[rowl[i] * HID + ncol0 + ni * 16] = (bf16_t)fast_tanh(v);
        }
    }

    // tokens for t=1 (prefetched)
    int tk[8];
#pragma unroll
    for (int i = 0; i < 8; i++) tk[i] = x[rowl[i] * SEN + 1];

    // ---- first sync: ALWAYS full release/acquire; publishes XCD mask
    __syncthreads();   // drains t0 stores AND the B-DMA (vmcnt covers global_load_lds)
    if (tid == 0) {
        const int my_xcd = (int)__builtin_amdgcn_s_getreg((3 << 11) | 20);  // HW_REG_XCC_ID
        __hip_atomic_fetch_or(xmask, 1 << my_xcd, __ATOMIC_RELAXED, __HIP_MEMORY_SCOPE_AGENT);
        __hip_atomic_fetch_add(cnt, 1, __ATOMIC_RELEASE, __HIP_MEMORY_SCOPE_AGENT);
        while (__hip_atomic_load(cnt, __ATOMIC_ACQUIRE, __HIP_MEMORY_SCOPE_AGENT) < PANEL_BLKS)
            __builtin_amdgcn_s_sleep(1);
        const int m = __hip_atomic_load(xmask, __ATOMIC_RELAXED, __HIP_MEMORY_SCOPE_AGENT);
        uni_sh = ((m & (m - 1)) == 0);   // one XCD bit -> same-L2 fast path legal
    }
    __syncthreads();
    asm volatile("buffer_inv" ::: "memory");
    const int fast = uni_sh;

#pragma unroll 1
    for (int t = 1; t < SEN; t++) {
        const bf16_t* h_in  = hbuf + (size_t)((t + 1) & 1) * (BATCH * HID);
        bf16_t*       h_out = hbuf + (size_t)(t & 1) * (BATCH * HID);

        floatx4 acc[2][2];
#pragma unroll
        for (int i = 0; i < 2; i++)
#pragma unroll
            for (int j = 0; j < 2; j++) acc[i][j] = (floatx4){0.f, 0.f, 0.f, 0.f};

        // A-fragment base: lane (q,l16), m-frag mf -> h_in[m0+mpos*32+mf*16+l16][c*32+q*8]
        const bf16_t* hA = h_in + (size_t)(m0 + mpos * 32 + l16) * HID + q * 8;

        bf16x8 afr[8][2];   // depth-8 chunk ring (64 VGPR): distance ~480cyc

        // prologue: prefetch chunks 0..7 (16 x 16B loads in flight)
#pragma unroll
        for (int d = 0; d < 8; d++) {
            afr[d][0] = *(const bf16x8*)(hA + d * 32);
            afr[d][1] = *(const bf16x8*)(hA + 16 * HID + d * 32);
        }

        // proj rows for THIS step (tk prefetched last step); used at epilogue
        float pv[8][2];
#pragma unroll
        for (int i = 0; i < 8; i++) {
            const float* pr = proj + tk[i] * HID + ncol0;
            pv[i][0] = pr[0];
            pv[i][1] = pr[16];
        }
        SB();

        // ---- main ring: compute chunk c (2 B ds_reads + 4 MFMA), refill c+8
#pragma unroll
        for (int c = 0; c < 32; c++) {
            const int slot = c & 7;
            const int pq = ((4 * c + q) ^ l7) * 8;   // swizzled 16B slot in row
            bf16x8 b0 = *(const bf16x8*)&Bsh[l16][pq];
            bf16x8 b1 = *(const bf16x8*)&Bsh[16 + l16][pq];
            acc[0][0] = __builtin_amdgcn_mfma_f32_16x16x32_bf16(afr[slot][0], b0, acc[0][0], 0, 0, 0);
            acc[0][1] = __builtin_amdgcn_mfma_f32_16x16x32_bf16(afr[slot][0], b1, acc[0][1], 0, 0, 0);
            acc[1][0] = __builtin_amdgcn_mfma_f32_16x16x32_bf16(afr[slot][1], b0, acc[1][0], 0, 0, 0);
            acc[1][1] = __builtin_amdgcn_mfma_f32_16x16x32_bf16(afr[slot][1], b1, acc[1][1], 0, 0, 0);
            if (c < 24) {
                afr[slot][0] = *(const bf16x8*)(hA + (c + 8) * 32);
                afr[slot][1] = *(const bf16x8*)(hA + 16 * HID + (c + 8) * 32);
            }
            if (c == 24 && t < SEN - 1) {   // tokens for t+1, off critical path
#pragma unroll
                for (int i = 0; i < 8; i++) tk[i] = x[rowl[i] * SEN + t + 1];
            }
            SB();
        }

        // epilogue: + proj, tanh, store (8 rows x 2 cols per lane)
#pragma unroll
        for (int mf = 0; mf < 2; mf++)
#pragma unroll
            for (int r = 0; r < 4; r++)
#pragma unroll
                for (int ni = 0; ni < 2; ni++) {
                    const int i = mf * 4 + r;
                    const float v = acc[mf][ni][r] + pv[i][ni];
                    h_out[rowl[i] * HID + ncol0 + ni * 16] = (bf16_t)fast_tanh(v);
                }

        // ---- panel sync (skip after final step) ---------------------------
        if (t < SEN - 1) {
            __syncthreads();   // vmcnt(0): this block's h stores are in L2
            if (fast) {        // same-L2: relaxed counter, no cache maintenance
                if (tid == 0) {
                    __hip_atomic_fetch_add(cnt, 1, __ATOMIC_RELAXED, __HIP_MEMORY_SCOPE_AGENT);
                    while (__hip_atomic_load(cnt, __ATOMIC_RELAXED, __HIP_MEMORY_SCOPE_AGENT)
                           < PANEL_BLKS * (t + 1))
                        __builtin_amdgcn_s_sleep(1);
                }
            } else {           // cross-XCD fallback: full release/acquire
                if (tid == 0) {
                    __hip_atomic_fetch_add(cnt, 1, __ATOMIC_RELEASE, __HIP_MEMORY_SCOPE_AGENT);
                    while (__hip_atomic_load(cnt, __ATOMIC_ACQUIRE, __HIP_MEMORY_SCOPE_AGENT)
                           < PANEL_BLKS * (t + 1))
                        __builtin_amdgcn_s_sleep(1);
                }
            }
            __syncthreads();
            // invalidate CU L1 so step-t h is re-read from (fresh) XCD L2
            asm volatile("buffer_inv" ::: "memory");
        }
    }
}

// ---------------- classifier: out = h @ W_cls^T + b_cls via MFMA (proven R2) ----------------
#define CBM 128
#define CLDK 72
__global__ __launch_bounds__(256)
void classifier_mfma(const bf16_t* __restrict__ h, const bf16_t* __restrict__ wcls,
                     const float* __restrict__ bcls, float* __restrict__ out)
{
    __shared__ __align__(16) bf16_t Ash[CBM][CLDK];
    __shared__ __align__(16) bf16_t Bsh[80][CLDK];

    const int tid = threadIdx.x;
    const int m0 = blockIdx.x * CBM;
    const int wave = tid >> 6, lane = tid & 63;
    const int wm = wave * 32;
    const int q = lane >> 4, l16 = lane & 15;

    floatx4 acc[2][5];
#pragma unroll
    for (int i = 0; i < 2; i++)
#pragma unroll
        for (int j = 0; j < 5; j++) acc[i][j] = (floatx4){0.f, 0.f, 0.f, 0.f};

    for (int kk = 0; kk < HID; kk += 64) {
#pragma unroll
        for (int it = 0; it < 4; it++) {
            int idx = tid + it * 256, r = idx >> 3, c = (idx & 7) * 8;
            *(uint4*)&Ash[r][c] = *(const uint4*)&h[(m0 + r) * HID + kk + c];
        }
#pragma unroll
        for (int it = 0; it < 3; it++) {
            int idx = tid + it * 256;
            if (idx < 640) {
                int r = idx >> 3, c = (idx & 7) * 8;
                *(uint4*)&Bsh[r][c] = *(const uint4*)&wcls[r * HID + kk + c];
            }
        }
        __syncthreads();
#pragma unroll
        for (int ks = 0; ks < 64; ks += 32) {
            bf16x8 af[2], bfr[5];
#pragma unroll
            for (int mi = 0; mi < 2; mi++)
                af[mi] = *(const bf16x8*)&Ash[wm + mi * 16 + l16][ks + q * 8];
#pragma unroll
            for (int ni = 0; ni < 5; ni++)
                bfr[ni] = *(const bf16x8*)&Bsh[ni * 16 + l16][ks + q * 8];
#pragma unroll
            for (int mi = 0; mi < 2; mi++)
#pragma unroll
                for (int ni = 0; ni < 5; ni++)
                    acc[mi][ni] = __builtin_amdgcn_mfma_f32_16x16x32_bf16(
                        af[mi], bfr[ni], acc[mi][ni], 0, 0, 0);
        }
        __syncthreads();
    }

#pragma unroll
    for (int mi = 0; mi < 2; mi++) {
#pragma unroll
        for (int r = 0; r < 4; r++) {
            int gm = m0 + wm + mi * 16 + q * 4 + r;
#pragma unroll
            for (int ni = 0; ni < 5; ni++) {
                int gn = ni * 16 + l16;
                if (gn < SEN + 1)
                    out[gm * (SEN + 1) + gn] = acc[mi][ni][r] + bcls[gn];
            }
        }
    }
}

extern "C" void kernel_launch(void* const* d_in, const int* in_sizes, int n_in,
                              void* d_out, int out_size, void* d_ws, size_t ws_size,
                              hipStream_t stream)
{
    const int*   x     = (const int*)  d_in[0];
    const float* emb   = (const float*)d_in[1];
    const float* w_ih  = (const float*)d_in[2];
    const float* w_hh  = (const float*)d_in[3];
    const float* w_cls = (const float*)d_in[4];
    const float* b_cls = (const float*)d_in[5];
    float* out = (float*)d_out;

    char* ws = (char*)d_ws;
    bf16_t* whh_bf  = (bf16_t*)ws;                                  // 2 MB
    float*  proj    = (float*)(ws + (2u << 20));                    // 128 KB
    bf16_t* wcls_bf = (bf16_t*)(ws + (2u << 20) + (128u << 10));    // 160 KB
    bf16_t* h0      = (bf16_t*)(ws + (2u << 20) + (288u << 10));    // 4 MB
    bf16_t* h1      = (bf16_t*)(ws + (6u << 20) + (288u << 10));    // 4 MB
    int*    scnt    = (int*)   (ws + (10u << 20) + (288u << 10));   // sync area

    hipMemsetAsync(scnt, 0, 16384, stream);
    cvt_whh<<<(HID * HID) / 256, 256, 0, stream>>>(w_hh, whh_bf, HID * HID);
    proj_kernel<<<(VOCAB * HID + 255) / 256, 256, 0, stream>>>(emb, w_ih, proj);
    cvt_wcls<<<(80 * HID) / 256, 256, 0, stream>>>(w_cls, wcls_bf);

    dim3 grid(BATCH / BM, HID / BN);   // (16,32) = 512 blocks = 2/CU (64 KB LDS)
    rnn_persist<<<grid, 256, 0, stream>>>(whh_bf, proj, x, h0, scnt);

    classifier_mfma<<<BATCH / CBM, 256, 0, stream>>>(h1, wcls_bf, b_cls, out);
}

// Round 12
// 714.132 us; speedup vs baseline: 1.8142x; 1.8142x over previous
//
#include <hip/hip_runtime.h>
#include <hip/hip_bf16.h>

#define VOCAB 29
#define VEC   512
#define HID   1024
#define SEN   64
#define BATCH 2048

typedef __bf16 bf16_t;
typedef bf16_t bf16x8 __attribute__((ext_vector_type(8)));
typedef float  floatx4 __attribute__((ext_vector_type(4)));

// ---------------- prep: W_hh fp32 -> bf16 ----------------
__global__ void cvt_whh(const float* __restrict__ w, bf16_t* __restrict__ o, int n) {
    int i = blockIdx.x * blockDim.x + threadIdx.x;
    if (i < n) o[i] = (bf16_t)w[i];
}

// ---------------- prep: W_cls fp32 [65][1024] -> bf16 padded [80][1024] ----------------
__global__ void cvt_wcls(const float* __restrict__ w, bf16_t* __restrict__ o) {
    int i = blockIdx.x * blockDim.x + threadIdx.x;
    if (i >= 80 * HID) return;
    o[i] = (i < 65 * HID) ? (bf16_t)w[i] : (bf16_t)0.0f;
}

// ---------------- prep: proj[v][h] = dot(emb[v], W_ih[h]) (fp32) ----------------
__global__ void proj_kernel(const float* __restrict__ emb, const float* __restrict__ wih,
                            float* __restrict__ proj) {
    int idx = blockIdx.x * blockDim.x + threadIdx.x;
    if (idx >= VOCAB * HID) return;
    int v = idx / HID, h = idx % HID;
    const float* e = emb + v * VEC;
    const float* w = wih + h * VEC;
    float s = 0.f;
    for (int k = 0; k < VEC; k += 4) {
        float4 ev = *(const float4*)(e + k);
        float4 wv = *(const float4*)(w + k);
        s += ev.x * wv.x + ev.y * wv.y + ev.z * wv.z + ev.w * wv.w;
    }
    proj[idx] = s;
}

// exact identity tanh(x) = 1 - 2/(exp(2x)+1); fp32 rounding error << bf16 ulp
__device__ __forceinline__ float fast_tanh(float x) {
    float e = __expf(2.0f * x);
    return 1.0f - 2.0f / (e + 1.0f);
}

// async global->LDS 16B copy. LDS dest: wave-uniform base + lane*16 (HW rule).
__device__ __forceinline__ void load16_to_lds(const bf16_t* g, bf16_t* l) {
    auto gp = reinterpret_cast<const __attribute__((address_space(1))) unsigned int*>(
        reinterpret_cast<uintptr_t>(g));
    auto lp = reinterpret_cast<__attribute__((address_space(3))) unsigned int*>(
        static_cast<unsigned int>(reinterpret_cast<uintptr_t>(l)));
    __builtin_amdgcn_global_load_lds(gp, lp, 16, 0, 0);
}

// ============================================================================
// v13: v8 base (652us, best) + three surgical fixes sized to measured limits.
//   Session facts: (1) DS pipe is v8's floor (1024 ds_read_b128 + 4.1k
//   conflict cyc = 6.8us/step); (2) 512-thr kernels are HARD-capped at
//   ~128 VGPR (v8 104/v9 128/v10 128/v11 100) - any design needing more
//   spills or sinks; (3) batched ISSUE->SB->COMPUTE groups (v5) force
//   liveness, per-chunk interleave (v8/v11/v12) gets compressed/sunk.
//   Fixes: (a) A-prefetch groups of 4 chunks, dbuf ag[2][4]=32 VGPR ->
//   total ~124 fits the cap; distance 1 group ~300cyc >= post-inv L2 lat.
//   (b) buffer_inv moved BEFORE the spin (after own drain): L2 is the
//   intra-XCD coherence point; no h-address touched between inv and
//   flag-pass -> refills read L2-current; inv+cold-L1 window overlaps spin.
//   (c) everything else identical to v8 (numerics unchanged).
// ============================================================================
#define BM 128
#define BN 64
#define PANEL_BLKS 16
#define SB() __builtin_amdgcn_sched_barrier(0)

// issue A-loads for chunks C0..C0+3 into group buffer B (tile 16x64: 1 frag/chunk)
#define ISSUE_G4(B, C0)                                              \
    _Pragma("unroll")                                                \
    for (int j = 0; j < 4; j++)                                      \
        ag[B][j] = *(const bf16x8*)(hA + ((C0) + j) * 32);

// compute chunks C0..C0+3 from group buffer B: 4 x {4 ds_read_b128, 4 MFMA}
#define COMP_G4(B, C0)                                               \
    _Pragma("unroll")                                                \
    for (int j = 0; j < 4; j++) {                                    \
        const int c_ = (C0) + j;                                     \
        const int pq = ((4 * c_ + q) ^ l7) * 8;                      \
        bf16x8 b0 = *(const bf16x8*)&Bsh[l16][pq];                   \
        bf16x8 b1 = *(const bf16x8*)&Bsh[16 + l16][pq];              \
        bf16x8 b2 = *(const bf16x8*)&Bsh[32 + l16][pq];              \
        bf16x8 b3 = *(const bf16x8*)&Bsh[48 + l16][pq];              \
        bf16x8 a0 = ag[B][j];                                        \
        acc[0] = __builtin_amdgcn_mfma_f32_16x16x32_bf16(a0, b0, acc[0], 0, 0, 0); \
        acc[1] = __builtin_amdgcn_mfma_f32_16x16x32_bf16(a0, b1, acc[1], 0, 0, 0); \
        acc[2] = __builtin_amdgcn_mfma_f32_16x16x32_bf16(a0, b2, acc[2], 0, 0, 0); \
        acc[3] = __builtin_amdgcn_mfma_f32_16x16x32_bf16(a0, b3, acc[3], 0, 0, 0); \
    }

__global__ __launch_bounds__(512, 2)
void rnn_persist(const bf16_t* __restrict__ whh, const float* __restrict__ proj,
                 const int* __restrict__ x, bf16_t* hbuf, int* scnt)
{
    __shared__ __align__(16) bf16_t Bsh[BN][HID];   // exactly 128 KB -> 1 block/CU
    __shared__ int uni_sh;

    const int tid  = threadIdx.x;
    const int bx   = blockIdx.x, by = blockIdx.y;
    const int m0   = bx * BM;
    const int n0   = by * BN;
    const int wave = tid >> 6;         // 8 waves
    const int lane = tid & 63;
    const int wm   = wave * 16;        // wave tile 16 x 64 (m-split 8 ways)
    const int q    = lane >> 4;
    const int l16  = lane & 15;
    const int l7   = l16 & 7;

    int* cnt   = scnt + bx * 64;            // per-panel counter (256B stride)
    int* xmask = scnt + (16 + bx) * 64;     // per-panel XCD mask

    // ---- stage W_hh slice ONCE: 8 waves x 8 rows per half; dest lane-linear
    //      (DMA rule), source 16B-chunk XOR'd: phys = glob ^ (r&7).
#pragma unroll
    for (int half = 0; half < 2; half++)
#pragma unroll
        for (int it = 0; it < 8; it++) {
            const int r = it * 8 + wave;
            load16_to_lds(whh + (n0 + r) * HID + half * 512 + (lane ^ (r & 7)) * 8,
                          &Bsh[r][half * 512 + lane * 8]);
        }

    // rows this lane owns (C/D row = q*4+reg, col = l16)
    int rowl[4];
#pragma unroll
    for (int r = 0; r < 4; r++) rowl[r] = m0 + wm + q * 4 + r;

    // ---- t = 0: h = tanh(proj[x[:,0]]) (h_prev = 0)
    {
        float pv0[4][4];
#pragma unroll
        for (int i = 0; i < 4; i++) {
            const int tok = x[rowl[i] * SEN + 0];
            const float* pr = proj + tok * HID + n0;
#pragma unroll
            for (int ni = 0; ni < 4; ni++) pv0[i][ni] = pr[ni * 16 + l16];
        }
#pragma unroll
        for (int i = 0; i < 4; i++)
#pragma unroll
            for (int ni = 0; ni < 4; ni++)
                hbuf[rowl[i] * HID + n0 + ni * 16 + l16] = (bf16_t)fast_tanh(pv0[i][ni]);
    }

    // tokens for t=1 (prefetched)
    int tk[4];
#pragma unroll
    for (int i = 0; i < 4; i++) tk[i] = x[rowl[i] * SEN + 1];

    // ---- first sync: ALWAYS full release/acquire; publishes XCD mask
    __syncthreads();   // drains t0 stores AND the B-DMA (vmcnt covers global_load_lds)
    if (tid == 0) {
        const int my_xcd = (int)__builtin_amdgcn_s_getreg((3 << 11) | 20);  // HW_REG_XCC_ID
        __hip_atomic_fetch_or(xmask, 1 << my_xcd, __ATOMIC_RELAXED, __HIP_MEMORY_SCOPE_AGENT);
        __hip_atomic_fetch_add(cnt, 1, __ATOMIC_RELEASE, __HIP_MEMORY_SCOPE_AGENT);
        while (__hip_atomic_load(cnt, __ATOMIC_ACQUIRE, __HIP_MEMORY_SCOPE_AGENT) < PANEL_BLKS)
            __builtin_amdgcn_s_sleep(1);
        const int m = __hip_atomic_load(xmask, __ATOMIC_RELAXED, __HIP_MEMORY_SCOPE_AGENT);
        uni_sh = ((m & (m - 1)) == 0);   // one XCD bit -> same-L2 fast path legal
    }
    __syncthreads();
    asm volatile("buffer_inv" ::: "memory");
    const int fast = uni_sh;

#pragma unroll 1
    for (int t = 1; t < SEN; t++) {
        const bf16_t* h_in  = hbuf + (size_t)((t + 1) & 1) * (BATCH * HID);
        bf16_t*       h_out = hbuf + (size_t)(t & 1) * (BATCH * HID);

        floatx4 acc[4];
#pragma unroll
        for (int j = 0; j < 4; j++) acc[j] = (floatx4){0.f, 0.f, 0.f, 0.f};

        // A-fragment base: lane (q,l16) holds h_in[wm+l16][c*32 + q*8 .. +7]
        const bf16_t* hA = h_in + (size_t)(m0 + wm + l16) * HID + q * 8;
        bf16x8 ag[2][4];   // 2 groups x 4 chunks = 32 VGPR (fits the 128 cap)

        // ---- pinned pipeline: batched ISSUE / COMPUTE, dbuf ----------------
        ISSUE_G4(0, 0)
        ISSUE_G4(1, 4)
        // proj rows for THIS step (tk prefetched last step); used at epilogue
        float pv[4][4];
#pragma unroll
        for (int i = 0; i < 4; i++) {
            const float* pr = proj + tk[i] * HID + n0;
#pragma unroll
            for (int ni = 0; ni < 4; ni++) pv[i][ni] = pr[ni * 16 + l16];
        }
        SB();
#pragma unroll
        for (int g = 0; g < 8; g++) {
            COMP_G4(g & 1, g * 4)
            SB();
            if (g < 6) {
                ISSUE_G4(g & 1, (g + 2) * 4)
                SB();
            }
            if (g == 5 && t < SEN - 1) {   // tokens for t+1, off critical path
#pragma unroll
                for (int i = 0; i < 4; i++) tk[i] = x[rowl[i] * SEN + t + 1];
            }
        }

        // epilogue: + proj, tanh, store
#pragma unroll
        for (int r = 0; r < 4; r++)
#pragma unroll
            for (int ni = 0; ni < 4; ni++) {
                float v = acc[ni][r] + pv[r][ni];
                h_out[rowl[r] * HID + n0 + ni * 16 + l16] = (bf16_t)fast_tanh(v);
            }

        // ---- panel sync (skip after final step) ---------------------------
        if (t < SEN - 1) {
            __syncthreads();   // vmcnt(0): this block's h stores are in L2
            // inv EARLY: overlaps the spin. Safe: L2 is the intra-XCD
            // coherence point; no h-address is touched between inv and the
            // flag-pass, so any L1 refill after inv reads L2-current data.
            asm volatile("buffer_inv" ::: "memory");
            if (fast) {        // same-L2: relaxed counter, no cache maintenance
                if (tid == 0) {
                    __hip_atomic_fetch_add(cnt, 1, __ATOMIC_RELAXED, __HIP_MEMORY_SCOPE_AGENT);
                    while (__hip_atomic_load(cnt, __ATOMIC_RELAXED, __HIP_MEMORY_SCOPE_AGENT)
                           < PANEL_BLKS * (t + 1))
                        __builtin_amdgcn_s_sleep(1);
                }
            } else {           // cross-XCD fallback: full release/acquire
                if (tid == 0) {
                    __hip_atomic_fetch_add(cnt, 1, __ATOMIC_RELEASE, __HIP_MEMORY_SCOPE_AGENT);
                    while (__hip_atomic_load(cnt, __ATOMIC_ACQUIRE, __HIP_MEMORY_SCOPE_AGENT)
                           < PANEL_BLKS * (t + 1))
                        __builtin_amdgcn_s_sleep(1);
                }
            }
            __syncthreads();
        }
    }
}

#undef ISSUE_G4
#undef COMP_G4

// ---------------- classifier: out = h @ W_cls^T + b_cls via MFMA (proven R2) ----------------
#define CBM 128
#define CLDK 72
__global__ __launch_bounds__(256)
void classifier_mfma(const bf16_t* __restrict__ h, const bf16_t* __restrict__ wcls,
                     const float* __restrict__ bcls, float* __restrict__ out)
{
    __shared__ __align__(16) bf16_t Ash[CBM][CLDK];
    __shared__ __align__(16) bf16_t Bsh[80][CLDK];

    const int tid = threadIdx.x;
    const int m0 = blockIdx.x * CBM;
    const int wave = tid >> 6, lane = tid & 63;
    const int wm = wave * 32;
    const int q = lane >> 4, l16 = lane & 15;

    floatx4 acc[2][5];
#pragma unroll
    for (int i = 0; i < 2; i++)
#pragma unroll
        for (int j = 0; j < 5; j++) acc[i][j] = (floatx4){0.f, 0.f, 0.f, 0.f};

    for (int kk = 0; kk < HID; kk += 64) {
#pragma unroll
        for (int it = 0; it < 4; it++) {
            int idx = tid + it * 256, r = idx >> 3, c = (idx & 7) * 8;
            *(uint4*)&Ash[r][c] = *(const uint4*)&h[(m0 + r) * HID + kk + c];
        }
#pragma unroll
        for (int it = 0; it < 3; it++) {
            int idx = tid + it * 256;
            if (idx < 640) {
                int r = idx >> 3, c = (idx & 7) * 8;
                *(uint4*)&Bsh[r][c] = *(const uint4*)&wcls[r * HID + kk + c];
            }
        }
        __syncthreads();
#pragma unroll
        for (int ks = 0; ks < 64; ks += 32) {
            bf16x8 af[2], bfr[5];
#pragma unroll
            for (int mi = 0; mi < 2; mi++)
                af[mi] = *(const bf16x8*)&Ash[wm + mi * 16 + l16][ks + q * 8];
#pragma unroll
            for (int ni = 0; ni < 5; ni++)
                bfr[ni] = *(const bf16x8*)&Bsh[ni * 16 + l16][ks + q * 8];
#pragma unroll
            for (int mi = 0; mi < 2; mi++)
#pragma unroll
                for (int ni = 0; ni < 5; ni++)
                    acc[mi][ni] = __builtin_amdgcn_mfma_f32_16x16x32_bf16(
                        af[mi], bfr[ni], acc[mi][ni], 0, 0, 0);
        }
        __syncthreads();
    }

#pragma unroll
    for (int mi = 0; mi < 2; mi++) {
#pragma unroll
        for (int r = 0; r < 4; r++) {
            int gm = m0 + wm + mi * 16 + q * 4 + r;
#pragma unroll
            for (int ni = 0; ni < 5; ni++) {
                int gn = ni * 16 + l16;
                if (gn < SEN + 1)
                    out[gm * (SEN + 1) + gn] = acc[mi][ni][r] + bcls[gn];
            }
        }
    }
}

extern "C" void kernel_launch(void* const* d_in, const int* in_sizes, int n_in,
                              void* d_out, int out_size, void* d_ws, size_t ws_size,
                              hipStream_t stream)
{
    const int*   x     = (const int*)  d_in[0];
    const float* emb   = (const float*)d_in[1];
    const float* w_ih  = (const float*)d_in[2];
    const float* w_hh  = (const float*)d_in[3];
    const float* w_cls = (const float*)d_in[4];
    const float* b_cls = (const float*)d_in[5];
    float* out = (float*)d_out;

    char* ws = (char*)d_ws;
    bf16_t* whh_bf  = (bf16_t*)ws;                                  // 2 MB
    float*  proj    = (float*)(ws + (2u << 20));                    // 128 KB
    bf16_t* wcls_bf = (bf16_t*)(ws + (2u << 20) + (128u << 10));    // 160 KB
    bf16_t* h0      = (bf16_t*)(ws + (2u << 20) + (288u << 10));    // 4 MB
    bf16_t* h1      = (bf16_t*)(ws + (6u << 20) + (288u << 10));    // 4 MB
    int*    scnt    = (int*)   (ws + (10u << 20) + (288u << 10));   // sync area

    hipMemsetAsync(scnt, 0, 16384, stream);
    cvt_whh<<<(HID * HID) / 256, 256, 0, stream>>>(w_hh, whh_bf, HID * HID);
    proj_kernel<<<(VOCAB * HID + 255) / 256, 256, 0, stream>>>(emb, w_ih, proj);
    cvt_wcls<<<(80 * HID) / 256, 256, 0, stream>>>(w_cls, wcls_bf);

    dim3 grid(BATCH / BM, HID / BN);   // (16,16) = 256 blocks = 1/CU (128 KB LDS)
    rnn_persist<<<grid, 512, 0, stream>>>(whh_bf, proj, x, h0, scnt);

    classifier_mfma<<<BATCH / CBM, 256, 0, stream>>>(h1, wcls_bf, b_cls, out);
}